// Round 10
// baseline (154.442 us; speedup 1.0000x reference)
//
#include <hip/hip_runtime.h>
#include <stdint.h>

typedef __attribute__((ext_vector_type(8))) short bh8;       // 8 x bf16 (4 VGPR)
typedef __attribute__((ext_vector_type(4))) float f32x4;
typedef __attribute__((ext_vector_type(4))) unsigned short u16x4;
typedef __attribute__((ext_vector_type(8))) unsigned short u16x8;
typedef __attribute__((ext_vector_type(2))) unsigned int u32x2;

#define DEVI static __device__ __forceinline__

constexpr int B_ = 2, S_ = 2048, D_ = 1024, H_ = 16, E_ = 64;

// workspace layout (elements of ushort/bf16)
constexpr size_t OFF_XB  = 0;                              // x as bf16 [B*S, D]
constexpr size_t OFF_WQT = OFF_XB  + (size_t)B_*S_*D_;     // WqT [H, E, D]  } contiguous
constexpr size_t OFF_WKT = OFF_WQT + (size_t)H_*E_*D_;     // WkT [H, E, D]  } = one
constexpr size_t OFF_WVT = OFF_WKT + (size_t)H_*E_*D_;     // WvT [H, E, D]  } [3072,1024]
constexpr size_t OFF_WOT = OFF_WVT + (size_t)H_*E_*D_;     // WoT [D, D]
constexpr size_t OFF_Q   = OFF_WOT + (size_t)D_*D_;        // Q^T [B*H, E, S] (pre-scaled by 0.125*log2e)
constexpr size_t OFF_K   = OFF_Q   + (size_t)B_*H_*S_*E_;  // [B*H, S, E]
constexpr size_t OFF_VT  = OFF_K   + (size_t)B_*H_*S_*E_;  // [B*H, E, S]
constexpr size_t OFF_O   = OFF_VT  + (size_t)B_*H_*S_*E_;  // attn out concat [B*S, D]

DEVI unsigned short f2bf(float f) {
    union { float f; unsigned u; } v; v.f = f;
    unsigned u = v.u;
    return (unsigned short)((u + 0x7fffu + ((u >> 16) & 1u)) >> 16);
}

DEVI unsigned cvt_pk_bf16(float lo, float hi) {   // packs {lo,hi} -> 2 bf16 in one u32
    unsigned r;
    asm("v_cvt_pk_bf16_f32 %0, %1, %2" : "=v"(r) : "v"(lo), "v"(hi));
    return r;
}

DEVI void gload16(const void* g, void* l) {
    __builtin_amdgcn_global_load_lds(
        (const __attribute__((address_space(1))) unsigned int*)g,
        (__attribute__((address_space(3))) unsigned int*)l, 16, 0, 0);
}

DEVI f32x4 mfma16(bh8 a, bh8 b, f32x4 c) {
    return __builtin_amdgcn_mfma_f32_16x16x32_bf16(a, b, c, 0, 0, 0);
}

// counted-vmcnt barrier: prefetched loads stay in flight across the barrier.
template<int N> DEVI void vm_barrier() {
    asm volatile("s_waitcnt vmcnt(%0)" :: "i"(N) : "memory");
    __builtin_amdgcn_s_barrier();
    __builtin_amdgcn_sched_barrier(0);
}
DEVI void post_barrier() {
    __builtin_amdgcn_sched_barrier(0);
    __builtin_amdgcn_s_barrier();
    __builtin_amdgcn_sched_barrier(0);
}

// ---------------- prep: x -> bf16 ----------------
__global__ __launch_bounds__(256) void k_convert_x(const float* __restrict__ x,
                                                   unsigned short* __restrict__ ws) {
    const int i = blockIdx.x * 256 + threadIdx.x;   // one float4 each; n4 = 1048576
    const float4 v = ((const float4*)x)[i];
    u16x4 o = { f2bf(v.x), f2bf(v.y), f2bf(v.z), f2bf(v.w) };
    *(u16x4*)(ws + OFF_XB + (size_t)i * 4) = o;
}

// ---------------- prep: weights -> bf16, transposed ----------------
__global__ __launch_bounds__(256) void k_transpose_w(const float* __restrict__ Wq,
                                                     const float* __restrict__ Wk,
                                                     const float* __restrict__ Wv,
                                                     const float* __restrict__ Wo,
                                                     unsigned short* __restrict__ ws) {
    const int xi = blockIdx.x;   // 0..255
    const int z  = blockIdx.y;   // 0..3
    const int t  = threadIdx.x;
    __shared__ __align__(16) unsigned short tile[64][72];

    const float* src; unsigned short* dst;
    int inCols, inBase, outBase;
    if (z < 3) {
        src = (z == 0) ? Wq : (z == 1) ? Wk : Wv;
        dst = ws + ((z == 0) ? OFF_WQT : (z == 1) ? OFF_WKT : OFF_WVT);
        inCols = 64;
        inBase = xi * 64 * 64;
        const int h = xi >> 4, dt = xi & 15;
        outBase = h * 65536 + dt * 64;
    } else {
        src = Wo; dst = ws + OFF_WOT;
        inCols = 1024;
        const int et = xi >> 4, dt = xi & 15;
        inBase  = (dt * 64) * 1024 + et * 64;
        outBase = (et * 64) * 1024 + dt * 64;
    }
#pragma unroll
    for (int v = 0; v < 4; ++v) {
        const int flat = v * 256 + t;
        const int i = flat >> 4, j4 = (flat & 15) * 4;
        const float4 val = *(const float4*)(src + inBase + i * inCols + j4);
        tile[i][j4 + 0] = f2bf(val.x);
        tile[i][j4 + 1] = f2bf(val.y);
        tile[i][j4 + 2] = f2bf(val.z);
        tile[i][j4 + 3] = f2bf(val.w);
    }
    __syncthreads();
    const int j = t >> 2, iseg = (t & 3) * 16;
    u16x8 p0, p1;
#pragma unroll
    for (int u = 0; u < 8; ++u) p0[u] = tile[iseg + u][j];
#pragma unroll
    for (int u = 0; u < 8; ++u) p1[u] = tile[iseg + 8 + u][j];
    *(u16x8*)(dst + outBase + (size_t)j * 1024 + iseg)     = p0;
    *(u16x8*)(dst + outBase + (size_t)j * 1024 + iseg + 8) = p1;
}

// ---------------- GEMM mainloop: C(128x64) = A(128x1024) * B^T(64x1024)^T ----------------
// 2 LDS buffers (12 KB each), 2-deep prefetch, counted-vmcnt barriers.
// Per k-step: 3 gload16/wave -> steady 6 in flight, wait vmcnt(3).
// Small tile maximizes blocks/CU (6 at 24 KB LDS) -> block-level TLP hides latency.
DEVI void gemm_tile_128x64(const unsigned short* __restrict__ A,
                           const unsigned short* __restrict__ Bw,
                           unsigned short* lds,
                           f32x4 acc[2][4]) {
    const int lane = threadIdx.x & 63;
    const int w    = threadIdx.x >> 6;
    const int lr = lane & 15, lg = lane >> 4;
    const unsigned short* a0 = A  + (size_t)((w * 2 + 0) * 16 + lr) * D_ + lg * 8;
    const unsigned short* a1 = A  + (size_t)((w * 2 + 1) * 16 + lr) * D_ + lg * 8;
    const unsigned short* b0 = Bw + (size_t)(w * 16 + lr) * D_ + lg * 8;
    const int oA0 = (w * 2 + 0) * 512, oA1 = (w * 2 + 1) * 512, oB = 8 * 512 + w * 512;

    auto stage = [&](int ks, int bufi) {
        unsigned short* base = lds + bufi * 6144;
        gload16(a0 + ks * 32, base + oA0);
        gload16(a1 + ks * 32, base + oA1);
        gload16(b0 + ks * 32, base + oB);
    };

    stage(0, 0); stage(1, 1);
    for (int ks = 0; ks < 32; ++ks) {
        if (ks < 31) vm_barrier<3>();   // tile ks landed; tile ks+1 in flight
        else         vm_barrier<0>();
        const unsigned short* base = lds + (ks & 1) * 6144;
        bh8 af0 = *(const bh8*)(base + (w * 2 + 0) * 512 + lane * 8);
        bh8 af1 = *(const bh8*)(base + (w * 2 + 1) * 512 + lane * 8);
#pragma unroll
        for (int nt = 0; nt < 4; ++nt) {
            bh8 bf = *(const bh8*)(base + 8 * 512 + nt * 512 + lane * 8);
            acc[0][nt] = mfma16(af0, bf, acc[0][nt]);
            acc[1][nt] = mfma16(af1, bf, acc[1][nt]);
        }
        post_barrier();                 // all waves done reading buf[ks&1]
        if (ks + 2 < 32) stage(ks + 2, ks & 1);
    }
}

// ---------------- fused QKV projection: C[4096,3072] = XB * [WqT;WkT;WvT]^T ----------------
// 128x64 tiles, grid 1536 = 6 blocks/CU (24 waves/CU) -> TLP hides staging latency.
// XCD decode keeps per-XCD A panel at 1 MB (L2-resident).
__global__ __launch_bounds__(256, 6) void k_qkv(unsigned short* __restrict__ ws,
                                                const float* __restrict__ bq,
                                                const float* __restrict__ bk,
                                                const float* __restrict__ bv) {
    const int flat  = blockIdx.x;                   // 0..1535
    const int xcd   = flat & 7;
    const int idx   = flat >> 3;                    // 0..191
    const int stile = xcd * 4 + (idx & 3);          // 0..31 (128 rows each)
    const int ntile = idx >> 2;                     // 0..47 (64 cols each of 3072)
    const int row0  = stile * 128;
    const int mat   = ntile >> 4;                   // 0=Q 1=K 2=V
    const int h     = ntile & 15;
    const unsigned short* A  = ws + OFF_XB  + (size_t)row0 * D_;
    const unsigned short* Bw = ws + OFF_WQT + (size_t)ntile * 64 * D_;
    const float* bias = ((mat == 0) ? bq : (mat == 1) ? bk : bv) + h * 64;

    __shared__ __align__(16) unsigned short lds[2 * 6144];   // 24 KB
    f32x4 acc[2][4];
#pragma unroll
    for (int i = 0; i < 2; ++i)
#pragma unroll
        for (int j = 0; j < 4; ++j) acc[i][j] = (f32x4){0.f, 0.f, 0.f, 0.f};

    gemm_tile_128x64(A, Bw, lds, acc);

    const int lane = threadIdx.x & 63, w = threadIdx.x >> 6;
    const int lr = lane & 15, lg = lane >> 4;
    const int srow0 = row0 + w * 32;
    const int b     = srow0 >> 11;
    const int sl0   = srow0 & (S_ - 1);
    const int bh    = b * H_ + h;
#pragma unroll
    for (int mt = 0; mt < 2; ++mt) {
#pragma unroll
        for (int nt = 0; nt < 4; ++nt) {
            const int e = nt * 16 + lr;
            const float bia = bias[e];
            if (mat == 0) {        // Q^T [BH][E][S], packed along s, pre-scaled
                u16x4 pk;
#pragma unroll
                for (int r = 0; r < 4; ++r)
                    pk[r] = f2bf((acc[mt][nt][r] + bia) * 0.1803368801f);  // 1/8*log2(e)
                const int sl = sl0 + mt * 16 + lg * 4;
                *(u16x4*)(ws + OFF_Q + ((size_t)(bh * E_ + e)) * S_ + sl) = pk;
            } else if (mat == 2) { // V^T [BH][E][S]
                u16x4 pk;
#pragma unroll
                for (int r = 0; r < 4; ++r) pk[r] = f2bf(acc[mt][nt][r] + bia);
                const int sl = sl0 + mt * 16 + lg * 4;
                *(u16x4*)(ws + OFF_VT + ((size_t)(bh * E_ + e)) * S_ + sl) = pk;
            } else {               // K [BH][S][E]
#pragma unroll
                for (int r = 0; r < 4; ++r) {
                    const int sl = sl0 + mt * 16 + lg * 4 + r;
                    ws[OFF_K + ((size_t)bh * S_ + sl) * E_ + e] = f2bf(acc[mt][nt][r] + bia);
                }
            }
        }
    }
}

// ---------------- flash attention (causal), swapped-QK^T in-lane softmax ----------------
__global__ __launch_bounds__(256, 4) void k_attn(unsigned short* __restrict__ ws) {
    const int flat = blockIdx.x;          // 0..1023
    const int j    = flat & 31;
    const int qt   = 31 - (flat >> 5);    // heavy tiles first
    const int bh   = (j & 7) * 4 + (j >> 3);
    const int lane = threadIdx.x & 63, w = threadIdx.x >> 6;
    const int lr = lane & 15, lg = lane >> 4;
    const unsigned short* Qp = ws + OFF_Q  + (size_t)bh * E_ * S_;   // Q^T [E][S]
    const unsigned short* Kp = ws + OFF_K  + (size_t)bh * S_ * E_;
    const unsigned short* Vp = ws + OFF_VT + (size_t)bh * E_ * S_;
    __shared__ __align__(16) unsigned short ldsK[2][8 * 512];
    __shared__ __align__(16) unsigned short ldsV[2][8 * 512];
    __shared__ __align__(16) unsigned short ldsP[4 * 1024];   // per-wave 16x64 P (wave-private)

    const int qbase = qt * 64 + w * 16;   // this wave's 16 q rows
    bh8 qf[2];
#pragma unroll
    for (int kg = 0; kg < 2; ++kg) {
        bh8 t;
#pragma unroll
        for (int i = 0; i < 8; ++i)
            t[i] = (short)Qp[(size_t)(kg * 32 + lg * 8 + i) * S_ + qbase + lr];
        qf[kg] = t;
    }

    f32x4 o[4];
    float m = -3.0e38f, l = 0.f;    // per-lane online state for q = lr (replicated over lg)
#pragma unroll
    for (int i = 0; i < 4; ++i) o[i] = (f32x4){0.f, 0.f, 0.f, 0.f};

    auto stage = [&](int kt, int bufi) {
        const int sk0 = kt * 64;
#pragma unroll
        for (int u = 0; u < 2; ++u) {
            const int blk = w * 2 + u;
            const int ct = blk >> 1, kg = blk & 1;
            gload16(Kp + (size_t)(sk0 + ct * 16 + lr) * E_ + kg * 32 + lg * 8,
                    &ldsK[bufi][blk * 512]);
            gload16(Vp + (size_t)(ct * 16 + lr) * S_ + sk0 + kg * 32 + lg * 8,
                    &ldsV[bufi][blk * 512]);
        }
    };

    unsigned short* Pw = ldsP + w * 1024;

    stage(0, 0);
    if (qt >= 1) stage(1, 1);

    for (int kt = 0; kt <= qt; ++kt) {
        if (kt < qt) vm_barrier<4>();
        else         vm_barrier<0>();
        const int cur = kt & 1;
        const unsigned short* Kc = ldsK[cur];
        const unsigned short* Vc = ldsV[cur];

        // S^T = K Q^T (swapped): sc[ct][r] = score[s_k = ct*16+lg*4+r][q = lr]
        f32x4 sc[4];
#pragma unroll
        for (int ct = 0; ct < 4; ++ct) sc[ct] = (f32x4){0.f, 0.f, 0.f, 0.f};
#pragma unroll
        for (int ct = 0; ct < 4; ++ct)
#pragma unroll
            for (int kg = 0; kg < 2; ++kg) {
                bh8 kf = *(const bh8*)(Kc + (ct * 2 + kg) * 512 + lane * 8);
                sc[ct] = mfma16(kf, qf[kg], sc[ct]);
            }
        // causal mask: diagonal tile only; local: s_k = ct*16+lg*4+r, q = w*16+lr
        if (kt == qt) {
#pragma unroll
            for (int ct = 0; ct < 4; ++ct) {
                const int skl = ct * 16 + lg * 4;
#pragma unroll
                for (int r = 0; r < 4; ++r)
                    if (skl + r > w * 16 + lr) sc[ct][r] = -3.0e38f;
            }
        }
        // column (q) max: 15 in-lane fmax + 2 shfl
        float mx = fmaxf(fmaxf(sc[0][0], sc[0][1]), fmaxf(sc[0][2], sc[0][3]));
#pragma unroll
        for (int ct = 1; ct < 4; ++ct)
            mx = fmaxf(mx, fmaxf(fmaxf(sc[ct][0], sc[ct][1]),
                                 fmaxf(sc[ct][2], sc[ct][3])));
        mx = fmaxf(mx, __shfl_xor(mx, 16, 64));
        mx = fmaxf(mx, __shfl_xor(mx, 32, 64));
        // defer-max (T13): rescale only when max grew by > 8 (log2 domain)
        const bool need = mx > m + 8.0f;
        if (__any(need)) {
            const float mn = need ? mx : m;
            const float sf = __builtin_amdgcn_exp2f(m - mn);   // 1.0 when !need
            m = mn;
            l *= sf;
#pragma unroll
            for (int r = 0; r < 4; ++r) {
                const float sfq = __shfl(sf, (lane & 48) + lg * 4 + r, 64);
#pragma unroll
                for (int et = 0; et < 4; ++et) o[et][r] *= sfq;
            }
        }
        // P = exp2(S - m), partial sum in-lane
        float rs = 0.f;
#pragma unroll
        for (int ct = 0; ct < 4; ++ct)
#pragma unroll
            for (int r = 0; r < 4; ++r) {
                float p = __builtin_amdgcn_exp2f(sc[ct][r] - m);
                sc[ct][r] = p;
                rs += p;
            }
        rs += __shfl_xor(rs, 16, 64);
        rs += __shfl_xor(rs, 32, 64);
        l += rs;
        // pack P (cvt_pk) and write A-frag order: 4 x ds_write_b64
#pragma unroll
        for (int ct = 0; ct < 4; ++ct) {
            u32x2 pk = { cvt_pk_bf16(sc[ct][0], sc[ct][1]),
                         cvt_pk_bf16(sc[ct][2], sc[ct][3]) };
            const int addr = (ct >> 1) * 512 +
                             ((((ct & 1) * 2) + (lg >> 1)) * 16 + lr) * 8 + (lg & 1) * 4;
            *(u32x2*)(Pw + addr) = pk;
        }
        // O += P V  (wave-private P; lgkm-ordered, no barrier)
#pragma unroll
        for (int skg = 0; skg < 2; ++skg) {
            bh8 pf = *(const bh8*)(Pw + skg * 512 + lane * 8);
#pragma unroll
            for (int et = 0; et < 4; ++et) {
                bh8 vf = *(const bh8*)(Vc + (et * 2 + skg) * 512 + lane * 8);
                o[et] = mfma16(pf, vf, o[et]);
            }
        }
        post_barrier();
        if (kt + 2 <= qt) stage(kt + 2, cur);
    }
    // epilogue: O/l -> concat layout [B,S,H*64]; l lives at lane with lr = q
    const int b = bh >> 4, hh = bh & 15;
#pragma unroll
    for (int r = 0; r < 4; ++r) {
        const float lq = __shfl(l, (lane & 48) + lg * 4 + r, 64);
        const float inv = 1.0f / lq;
        const int s = qbase + lg * 4 + r;
#pragma unroll
        for (int et = 0; et < 4; ++et)
            ws[OFF_O + ((size_t)(b * S_ + s)) * D_ + hh * E_ + et * 16 + lr] =
                f2bf(o[et][r] * inv);
    }
}

// ---------------- output projection: C[4096,1024] = O * WoT^T ----------------
// 128x64 tiles -> grid 512 = 2 blocks/CU (double of the 128x128 version).
__global__ __launch_bounds__(256, 6) void k_oproj(const unsigned short* __restrict__ ws,
                                                  const float* __restrict__ bo,
                                                  float* __restrict__ out) {
    const int flat  = blockIdx.x;                   // 0..511
    const int xcd   = flat & 7;
    const int idx   = flat >> 3;                    // 0..63
    const int stile = xcd * 4 + (idx & 3);          // 0..31
    const int ntile = idx >> 2;                     // 0..15 (64 cols each)
    const unsigned short* A  = ws + OFF_O   + (size_t)stile * 128 * D_;
    const unsigned short* Bw = ws + OFF_WOT + (size_t)ntile * 64 * D_;
    __shared__ __align__(16) unsigned short lds[2 * 6144];
    f32x4 acc[2][4];
#pragma unroll
    for (int i = 0; i < 2; ++i)
#pragma unroll
        for (int j = 0; j < 4; ++j) acc[i][j] = (f32x4){0.f, 0.f, 0.f, 0.f};

    gemm_tile_128x64(A, Bw, lds, acc);

    const int lane = threadIdx.x & 63, w = threadIdx.x >> 6;
    const int lr = lane & 15, lg = lane >> 4;
    const int r0 = stile * 128 + w * 32;
#pragma unroll
    for (int mt = 0; mt < 2; ++mt)
#pragma unroll
        for (int nt = 0; nt < 4; ++nt) {
            const int e = ntile * 64 + nt * 16 + lr;
            const float bia = bo[e];
#pragma unroll
            for (int r = 0; r < 4; ++r)
                out[(size_t)(r0 + mt * 16 + lg * 4 + r) * D_ + e] = acc[mt][nt][r] + bia;
        }
}

extern "C" void kernel_launch(void* const* d_in, const int* in_sizes, int n_in,
                              void* d_out, int out_size, void* d_ws, size_t ws_size,
                              hipStream_t stream) {
    const float* x  = (const float*)d_in[0];
    const float* Wq = (const float*)d_in[1];
    const float* bq = (const float*)d_in[2];
    const float* Wk = (const float*)d_in[3];
    const float* bk = (const float*)d_in[4];
    const float* Wv = (const float*)d_in[5];
    const float* bv = (const float*)d_in[6];
    const float* Wo = (const float*)d_in[7];
    const float* bo = (const float*)d_in[8];
    float* out = (float*)d_out;
    unsigned short* ws = (unsigned short*)d_ws;

    k_convert_x<<<dim3((B_ * S_ * D_) / 4 / 256), 256, 0, stream>>>(x, ws);
    k_transpose_w<<<dim3(256, 4), 256, 0, stream>>>(Wq, Wk, Wv, Wo, ws);
    k_qkv<<<dim3(1536), 256, 0, stream>>>(ws, bq, bk, bv);
    k_attn<<<dim3(1024), 256, 0, stream>>>(ws);
    k_oproj<<<dim3(512), 256, 0, stream>>>(ws, bo, out);
}

// Round 11
// 128.816 us; speedup vs baseline: 1.1989x; 1.1989x over previous
//
#include <hip/hip_runtime.h>
#include <stdint.h>

typedef __attribute__((ext_vector_type(8))) short bh8;       // 8 x bf16 (4 VGPR)
typedef __attribute__((ext_vector_type(4))) float f32x4;
typedef __attribute__((ext_vector_type(4))) unsigned short u16x4;
typedef __attribute__((ext_vector_type(8))) unsigned short u16x8;
typedef __attribute__((ext_vector_type(2))) unsigned int u32x2;

#define DEVI static __device__ __forceinline__

constexpr int B_ = 2, S_ = 2048, D_ = 1024, H_ = 16, E_ = 64;

// workspace layout (elements of ushort/bf16)
constexpr size_t OFF_XB  = 0;                              // x as bf16 [B*S, D]
constexpr size_t OFF_WQT = OFF_XB  + (size_t)B_*S_*D_;     // WqT [H, E, D]  } contiguous
constexpr size_t OFF_WKT = OFF_WQT + (size_t)H_*E_*D_;     // WkT [H, E, D]  } = one
constexpr size_t OFF_WVT = OFF_WKT + (size_t)H_*E_*D_;     // WvT [H, E, D]  } [3072,1024]
constexpr size_t OFF_WOT = OFF_WVT + (size_t)H_*E_*D_;     // WoT [D, D]
constexpr size_t OFF_Q   = OFF_WOT + (size_t)D_*D_;        // Q^T [B*H, E, S] (pre-scaled by 0.125*log2e)
constexpr size_t OFF_K   = OFF_Q   + (size_t)B_*H_*S_*E_;  // [B*H, S, E]
constexpr size_t OFF_VT  = OFF_K   + (size_t)B_*H_*S_*E_;  // [B*H, E, S]
constexpr size_t OFF_O   = OFF_VT  + (size_t)B_*H_*S_*E_;  // attn out concat [B*S, D]

DEVI unsigned short f2bf(float f) {
    union { float f; unsigned u; } v; v.f = f;
    unsigned u = v.u;
    return (unsigned short)((u + 0x7fffu + ((u >> 16) & 1u)) >> 16);
}

DEVI unsigned cvt_pk_bf16(float lo, float hi) {   // packs {lo,hi} -> 2 bf16 in one u32
    unsigned r;
    asm("v_cvt_pk_bf16_f32 %0, %1, %2" : "=v"(r) : "v"(lo), "v"(hi));
    return r;
}

DEVI void gload16(const void* g, void* l) {
    __builtin_amdgcn_global_load_lds(
        (const __attribute__((address_space(1))) unsigned int*)g,
        (__attribute__((address_space(3))) unsigned int*)l, 16, 0, 0);
}

DEVI f32x4 mfma16(bh8 a, bh8 b, f32x4 c) {
    return __builtin_amdgcn_mfma_f32_16x16x32_bf16(a, b, c, 0, 0, 0);
}

// counted-vmcnt barrier: prefetched loads stay in flight across the barrier.
template<int N> DEVI void vm_barrier() {
    asm volatile("s_waitcnt vmcnt(%0)" :: "i"(N) : "memory");
    __builtin_amdgcn_s_barrier();
    __builtin_amdgcn_sched_barrier(0);
}
DEVI void post_barrier() {
    __builtin_amdgcn_sched_barrier(0);
    __builtin_amdgcn_s_barrier();
    __builtin_amdgcn_sched_barrier(0);
}

// ---------------- prep: x -> bf16 ----------------
__global__ __launch_bounds__(256) void k_convert_x(const float* __restrict__ x,
                                                   unsigned short* __restrict__ ws) {
    const int i = blockIdx.x * 256 + threadIdx.x;   // one float4 each; n4 = 1048576
    const float4 v = ((const float4*)x)[i];
    u16x4 o = { f2bf(v.x), f2bf(v.y), f2bf(v.z), f2bf(v.w) };
    *(u16x4*)(ws + OFF_XB + (size_t)i * 4) = o;
}

// ---------------- prep: weights -> bf16, transposed ----------------
__global__ __launch_bounds__(256) void k_transpose_w(const float* __restrict__ Wq,
                                                     const float* __restrict__ Wk,
                                                     const float* __restrict__ Wv,
                                                     const float* __restrict__ Wo,
                                                     unsigned short* __restrict__ ws) {
    const int xi = blockIdx.x;   // 0..255
    const int z  = blockIdx.y;   // 0..3
    const int t  = threadIdx.x;
    __shared__ __align__(16) unsigned short tile[64][72];

    const float* src; unsigned short* dst;
    int inCols, inBase, outBase;
    if (z < 3) {
        src = (z == 0) ? Wq : (z == 1) ? Wk : Wv;
        dst = ws + ((z == 0) ? OFF_WQT : (z == 1) ? OFF_WKT : OFF_WVT);
        inCols = 64;
        inBase = xi * 64 * 64;
        const int h = xi >> 4, dt = xi & 15;
        outBase = h * 65536 + dt * 64;
    } else {
        src = Wo; dst = ws + OFF_WOT;
        inCols = 1024;
        const int et = xi >> 4, dt = xi & 15;
        inBase  = (dt * 64) * 1024 + et * 64;
        outBase = (et * 64) * 1024 + dt * 64;
    }
#pragma unroll
    for (int v = 0; v < 4; ++v) {
        const int flat = v * 256 + t;
        const int i = flat >> 4, j4 = (flat & 15) * 4;
        const float4 val = *(const float4*)(src + inBase + i * inCols + j4);
        tile[i][j4 + 0] = f2bf(val.x);
        tile[i][j4 + 1] = f2bf(val.y);
        tile[i][j4 + 2] = f2bf(val.z);
        tile[i][j4 + 3] = f2bf(val.w);
    }
    __syncthreads();
    const int j = t >> 2, iseg = (t & 3) * 16;
    u16x8 p0, p1;
#pragma unroll
    for (int u = 0; u < 8; ++u) p0[u] = tile[iseg + u][j];
#pragma unroll
    for (int u = 0; u < 8; ++u) p1[u] = tile[iseg + 8 + u][j];
    *(u16x8*)(dst + outBase + (size_t)j * 1024 + iseg)     = p0;
    *(u16x8*)(dst + outBase + (size_t)j * 1024 + iseg + 8) = p1;
}

// ---------------- GEMM mainloop: C(128x128) = A(128x1024) * B^T(128x1024)^T ----------------
// 3 LDS buffers, stage-at-top rotation -> ONE barrier per k-step (was 2).
// At iter ks: read buf[ks%3]; stage tile ks+2 into buf[(ks+2)%3], whose last
// readers (iter ks-1) all passed this iteration's barrier. Steady state: 2 tiles
// (8 loads/wave) in flight -> vmcnt(4). sched_barrier(0) at loop end pins the
// MFMAs + their lgkmcnt waits inside the iteration (ds_reads complete before the
// next barrier, so staging never overwrites a buffer with reads pending).
DEVI void gemm_tile_128x128(const unsigned short* __restrict__ A,
                            const unsigned short* __restrict__ Bw,
                            unsigned short* lds,
                            f32x4 acc[2][8]) {
    const int lane = threadIdx.x & 63;
    const int w    = threadIdx.x >> 6;
    const int lr = lane & 15, lg = lane >> 4;
    const unsigned short* a0 = A  + (size_t)((w * 2 + 0) * 16 + lr) * D_ + lg * 8;
    const unsigned short* a1 = A  + (size_t)((w * 2 + 1) * 16 + lr) * D_ + lg * 8;
    const unsigned short* b0 = Bw + (size_t)((w * 2 + 0) * 16 + lr) * D_ + lg * 8;
    const unsigned short* b1 = Bw + (size_t)((w * 2 + 1) * 16 + lr) * D_ + lg * 8;
    const int oA0 = (w * 2 + 0) * 512, oA1 = (w * 2 + 1) * 512;
    const int oB0 = 4096 + oA0,        oB1 = 4096 + oA1;

    auto stage = [&](int ks, int bufi) {
        unsigned short* base = lds + bufi * 8192;
        gload16(a0 + ks * 32, base + oA0);
        gload16(a1 + ks * 32, base + oA1);
        gload16(b0 + ks * 32, base + oB0);
        gload16(b1 + ks * 32, base + oB1);
    };

    stage(0, 0); stage(1, 1);
    for (int ks = 0; ks < 32; ++ks) {
        if (ks < 31) vm_barrier<4>();   // tile ks landed; tile ks+1 in flight
        else         vm_barrier<0>();
        if (ks + 2 < 32) stage(ks + 2, (ks + 2) % 3);   // freed by the barrier above
        const unsigned short* base = lds + (ks % 3) * 8192;
        bh8 af0 = *(const bh8*)(base + (w * 2 + 0) * 512 + lane * 8);
        bh8 af1 = *(const bh8*)(base + (w * 2 + 1) * 512 + lane * 8);
#pragma unroll
        for (int nt = 0; nt < 8; ++nt) {
            bh8 bf = *(const bh8*)(base + 4096 + nt * 512 + lane * 8);
            acc[0][nt] = mfma16(af0, bf, acc[0][nt]);
            acc[1][nt] = mfma16(af1, bf, acc[1][nt]);
        }
        __builtin_amdgcn_sched_barrier(0);   // keep reads+MFMAs inside this iter
    }
}

// ---------------- fused QKV projection: C[4096,3072] = XB * [WqT;WkT;WvT]^T ----------------
__global__ __launch_bounds__(256, 3) void k_qkv(unsigned short* __restrict__ ws,
                                                const float* __restrict__ bq,
                                                const float* __restrict__ bk,
                                                const float* __restrict__ bv) {
    const int flat  = blockIdx.x;          // 0..767
    const int idx   = flat >> 3;           // 0..95
    const int stile = (flat & 7) * 4 + (idx & 3);   // 0..31 (128 rows each)
    const int ntile = idx >> 2;            // 0..23 (128 cols each of 3072)
    const int row0  = stile * 128;
    const unsigned short* A  = ws + OFF_XB  + (size_t)row0 * D_;
    const unsigned short* Bw = ws + OFF_WQT + (size_t)ntile * 128 * D_;

    __shared__ __align__(16) unsigned short lds[3 * 8192];
    f32x4 acc[2][8];
#pragma unroll
    for (int i = 0; i < 2; ++i)
#pragma unroll
        for (int j = 0; j < 8; ++j) acc[i][j] = (f32x4){0.f, 0.f, 0.f, 0.f};

    gemm_tile_128x128(A, Bw, lds, acc);

    const int lane = threadIdx.x & 63, w = threadIdx.x >> 6;
    const int lr = lane & 15, lg = lane >> 4;
    const int srow0 = row0 + w * 32;
    const int b     = srow0 >> 11;
    const int sl0   = srow0 & (S_ - 1);
#pragma unroll
    for (int mt = 0; mt < 2; ++mt) {
#pragma unroll
        for (int nt = 0; nt < 8; ++nt) {
            const int gcol = ntile * 128 + nt * 16;
            const int mat  = gcol >> 10;
            const int h    = (gcol >> 6) & 15;
            const int e    = (gcol & 63) + lr;
            const int bh   = b * H_ + h;
            const float bia = ((mat == 0) ? bq : (mat == 1) ? bk : bv)[h * 64 + e];
            if (mat == 0) {        // Q^T [BH][E][S], packed along s, pre-scaled
                u16x4 pk;
#pragma unroll
                for (int r = 0; r < 4; ++r)
                    pk[r] = f2bf((acc[mt][nt][r] + bia) * 0.1803368801f);  // 1/8*log2(e)
                const int sl = sl0 + mt * 16 + lg * 4;
                *(u16x4*)(ws + OFF_Q + ((size_t)(bh * E_ + e)) * S_ + sl) = pk;
            } else if (mat == 2) { // V^T [BH][E][S]
                u16x4 pk;
#pragma unroll
                for (int r = 0; r < 4; ++r) pk[r] = f2bf(acc[mt][nt][r] + bia);
                const int sl = sl0 + mt * 16 + lg * 4;
                *(u16x4*)(ws + OFF_VT + ((size_t)(bh * E_ + e)) * S_ + sl) = pk;
            } else {               // K [BH][S][E]
#pragma unroll
                for (int r = 0; r < 4; ++r) {
                    const int sl = sl0 + mt * 16 + lg * 4 + r;
                    ws[OFF_K + ((size_t)bh * S_ + sl) * E_ + e] = f2bf(acc[mt][nt][r] + bia);
                }
            }
        }
    }
}

// ---------------- flash attention (causal), swapped-QK^T in-lane softmax ----------------
__global__ __launch_bounds__(256, 4) void k_attn(unsigned short* __restrict__ ws) {
    const int flat = blockIdx.x;          // 0..1023
    const int j    = flat & 31;
    const int qt   = 31 - (flat >> 5);    // heavy tiles first
    const int bh   = (j & 7) * 4 + (j >> 3);
    const int lane = threadIdx.x & 63, w = threadIdx.x >> 6;
    const int lr = lane & 15, lg = lane >> 4;
    const unsigned short* Qp = ws + OFF_Q  + (size_t)bh * E_ * S_;   // Q^T [E][S]
    const unsigned short* Kp = ws + OFF_K  + (size_t)bh * S_ * E_;
    const unsigned short* Vp = ws + OFF_VT + (size_t)bh * E_ * S_;
    __shared__ __align__(16) unsigned short ldsK[2][8 * 512];
    __shared__ __align__(16) unsigned short ldsV[2][8 * 512];
    __shared__ __align__(16) unsigned short ldsP[4 * 1024];   // per-wave 16x64 P (wave-private)

    const int qbase = qt * 64 + w * 16;   // this wave's 16 q rows
    bh8 qf[2];
#pragma unroll
    for (int kg = 0; kg < 2; ++kg) {
        bh8 t;
#pragma unroll
        for (int i = 0; i < 8; ++i)
            t[i] = (short)Qp[(size_t)(kg * 32 + lg * 8 + i) * S_ + qbase + lr];
        qf[kg] = t;
    }

    f32x4 o[4];
    float m = -3.0e38f, l = 0.f;    // per-lane online state for q = lr (replicated over lg)
#pragma unroll
    for (int i = 0; i < 4; ++i) o[i] = (f32x4){0.f, 0.f, 0.f, 0.f};

    auto stage = [&](int kt, int bufi) {
        const int sk0 = kt * 64;
#pragma unroll
        for (int u = 0; u < 2; ++u) {
            const int blk = w * 2 + u;
            const int ct = blk >> 1, kg = blk & 1;
            gload16(Kp + (size_t)(sk0 + ct * 16 + lr) * E_ + kg * 32 + lg * 8,
                    &ldsK[bufi][blk * 512]);
            gload16(Vp + (size_t)(ct * 16 + lr) * S_ + sk0 + kg * 32 + lg * 8,
                    &ldsV[bufi][blk * 512]);
        }
    };

    unsigned short* Pw = ldsP + w * 1024;

    stage(0, 0);
    if (qt >= 1) stage(1, 1);

    for (int kt = 0; kt <= qt; ++kt) {
        if (kt < qt) vm_barrier<4>();
        else         vm_barrier<0>();
        const int cur = kt & 1;
        const unsigned short* Kc = ldsK[cur];
        const unsigned short* Vc = ldsV[cur];

        // S^T = K Q^T (swapped): sc[ct][r] = score[s_k = ct*16+lg*4+r][q = lr]
        f32x4 sc[4];
#pragma unroll
        for (int ct = 0; ct < 4; ++ct) sc[ct] = (f32x4){0.f, 0.f, 0.f, 0.f};
#pragma unroll
        for (int ct = 0; ct < 4; ++ct)
#pragma unroll
            for (int kg = 0; kg < 2; ++kg) {
                bh8 kf = *(const bh8*)(Kc + (ct * 2 + kg) * 512 + lane * 8);
                sc[ct] = mfma16(kf, qf[kg], sc[ct]);
            }
        // causal mask: diagonal tile only; local: s_k = ct*16+lg*4+r, q = w*16+lr
        if (kt == qt) {
#pragma unroll
            for (int ct = 0; ct < 4; ++ct) {
                const int skl = ct * 16 + lg * 4;
#pragma unroll
                for (int r = 0; r < 4; ++r)
                    if (skl + r > w * 16 + lr) sc[ct][r] = -3.0e38f;
            }
        }
        // column (q) max: 15 in-lane fmax + 2 shfl
        float mx = fmaxf(fmaxf(sc[0][0], sc[0][1]), fmaxf(sc[0][2], sc[0][3]));
#pragma unroll
        for (int ct = 1; ct < 4; ++ct)
            mx = fmaxf(mx, fmaxf(fmaxf(sc[ct][0], sc[ct][1]),
                                 fmaxf(sc[ct][2], sc[ct][3])));
        mx = fmaxf(mx, __shfl_xor(mx, 16, 64));
        mx = fmaxf(mx, __shfl_xor(mx, 32, 64));
        // defer-max (T13): rescale only when max grew by > 8 (log2 domain)
        const bool need = mx > m + 8.0f;
        if (__any(need)) {
            const float mn = need ? mx : m;
            const float sf = __builtin_amdgcn_exp2f(m - mn);   // 1.0 when !need
            m = mn;
            l *= sf;
#pragma unroll
            for (int r = 0; r < 4; ++r) {
                const float sfq = __shfl(sf, (lane & 48) + lg * 4 + r, 64);
#pragma unroll
                for (int et = 0; et < 4; ++et) o[et][r] *= sfq;
            }
        }
        // P = exp2(S - m), partial sum in-lane
        float rs = 0.f;
#pragma unroll
        for (int ct = 0; ct < 4; ++ct)
#pragma unroll
            for (int r = 0; r < 4; ++r) {
                float p = __builtin_amdgcn_exp2f(sc[ct][r] - m);
                sc[ct][r] = p;
                rs += p;
            }
        rs += __shfl_xor(rs, 16, 64);
        rs += __shfl_xor(rs, 32, 64);
        l += rs;
        // pack P (cvt_pk) and write A-frag order: 4 x ds_write_b64
#pragma unroll
        for (int ct = 0; ct < 4; ++ct) {
            u32x2 pk = { cvt_pk_bf16(sc[ct][0], sc[ct][1]),
                         cvt_pk_bf16(sc[ct][2], sc[ct][3]) };
            const int addr = (ct >> 1) * 512 +
                             ((((ct & 1) * 2) + (lg >> 1)) * 16 + lr) * 8 + (lg & 1) * 4;
            *(u32x2*)(Pw + addr) = pk;
        }
        // O += P V  (wave-private P; lgkm-ordered, no barrier)
#pragma unroll
        for (int skg = 0; skg < 2; ++skg) {
            bh8 pf = *(const bh8*)(Pw + skg * 512 + lane * 8);
#pragma unroll
            for (int et = 0; et < 4; ++et) {
                bh8 vf = *(const bh8*)(Vc + (et * 2 + skg) * 512 + lane * 8);
                o[et] = mfma16(pf, vf, o[et]);
            }
        }
        post_barrier();
        if (kt + 2 <= qt) stage(kt + 2, cur);
    }
    // epilogue: O/l -> concat layout [B,S,H*64]; l lives at lane with lr = q
    const int b = bh >> 4, hh = bh & 15;
#pragma unroll
    for (int r = 0; r < 4; ++r) {
        const float lq = __shfl(l, (lane & 48) + lg * 4 + r, 64);
        const float inv = 1.0f / lq;
        const int s = qbase + lg * 4 + r;
#pragma unroll
        for (int et = 0; et < 4; ++et)
            ws[OFF_O + ((size_t)(b * S_ + s)) * D_ + hh * E_ + et * 16 + lr] =
                f2bf(o[et][r] * inv);
    }
}

// ---------------- output projection: C[4096,1024] = O * WoT^T ----------------
__global__ __launch_bounds__(256, 3) void k_oproj(const unsigned short* __restrict__ ws,
                                                  const float* __restrict__ bo,
                                                  float* __restrict__ out) {
    const int flat  = blockIdx.x;          // 0..255
    const int idx   = flat >> 3;           // 0..31
    const int stile = (flat & 7) * 4 + (idx & 3);   // 0..31
    const int ntile = idx >> 2;            // 0..7 (128 cols each)
    const unsigned short* A  = ws + OFF_O   + (size_t)stile * 128 * D_;
    const unsigned short* Bw = ws + OFF_WOT + (size_t)ntile * 128 * D_;
    __shared__ __align__(16) unsigned short lds[3 * 8192];
    f32x4 acc[2][8];
#pragma unroll
    for (int i = 0; i < 2; ++i)
#pragma unroll
        for (int j = 0; j < 8; ++j) acc[i][j] = (f32x4){0.f, 0.f, 0.f, 0.f};

    gemm_tile_128x128(A, Bw, lds, acc);

    const int lane = threadIdx.x & 63, w = threadIdx.x >> 6;
    const int lr = lane & 15, lg = lane >> 4;
    const int r0 = stile * 128 + w * 32;
#pragma unroll
    for (int mt = 0; mt < 2; ++mt)
#pragma unroll
        for (int nt = 0; nt < 8; ++nt) {
            const int e = ntile * 128 + nt * 16 + lr;
            const float bia = bo[e];
#pragma unroll
            for (int r = 0; r < 4; ++r)
                out[(size_t)(r0 + mt * 16 + lg * 4 + r) * D_ + e] = acc[mt][nt][r] + bia;
        }
}

extern "C" void kernel_launch(void* const* d_in, const int* in_sizes, int n_in,
                              void* d_out, int out_size, void* d_ws, size_t ws_size,
                              hipStream_t stream) {
    const float* x  = (const float*)d_in[0];
    const float* Wq = (const float*)d_in[1];
    const float* bq = (const float*)d_in[2];
    const float* Wk = (const float*)d_in[3];
    const float* bk = (const float*)d_in[4];
    const float* Wv = (const float*)d_in[5];
    const float* bv = (const float*)d_in[6];
    const float* Wo = (const float*)d_in[7];
    const float* bo = (const float*)d_in[8];
    float* out = (float*)d_out;
    unsigned short* ws = (unsigned short*)d_ws;

    k_convert_x<<<dim3((B_ * S_ * D_) / 4 / 256), 256, 0, stream>>>(x, ws);
    k_transpose_w<<<dim3(256, 4), 256, 0, stream>>>(Wq, Wk, Wv, Wo, ws);
    k_qkv<<<dim3(768), 256, 0, stream>>>(ws, bq, bk, bv);
    k_attn<<<dim3(1024), 256, 0, stream>>>(ws);
    k_oproj<<<dim3(256), 256, 0, stream>>>(ws, bo, out);
}